// Round 3
// baseline (1075.837 us; speedup 1.0000x reference)
//
#include <hip/hip_runtime.h>
#include <stdint.h>

// Problem constants (match reference)
#define NROWS 32768
#define NW    256                 // N_WORDS
#define LW    32                  // L_WORD
#define NMQ   (NROWS * NW)        // 8388608, elements per book-slice of soft_prob
#define HALFC 33554432u           // 4*NMQ (book offset in flat (8,N,M) index)
#define QSIZE (NROWS * 256)       // Q element count
#define LDC   33                  // padded leading dim for C tile in LDS

#define BLOCK 1024
#define WPB   (BLOCK / 64)        // 16 waves per block

__device__ __forceinline__ uint32_t rotl32(uint32_t x, unsigned r) {
    return (x << r) | (x >> (32u - r));
}

// JAX *partitionable* threefry path (default in modern JAX):
//   counts = (i >> 32, i & 0xffffffff) = (0, i) for i < 2^32; key = (0, 42)
//   bits1, bits2 = threefry2x32(key, counts)
//   bits[i] = bits1 ^ bits2            // 32-bit case in _threefry_random_bits_partitionable
__device__ __forceinline__ uint32_t tfp32(uint32_t idx) {
    const uint32_t K1 = 42u;
    const uint32_t K2 = 0x1BD11BDAu ^ 42u;
    uint32_t x0 = 0u;          // counts_hi (0) + ks[0] (0)
    uint32_t x1 = idx + K1;    // counts_lo + ks[1]
#define TFR(r) { x0 += x1; x1 = rotl32(x1, (r)) ^ x0; }
    TFR(13) TFR(15) TFR(26) TFR(6)
    x0 += K1; x1 += K2 + 1u;
    TFR(17) TFR(29) TFR(16) TFR(24)
    x0 += K2; x1 += 2u;              // + ks[0]
    TFR(13) TFR(15) TFR(26) TFR(6)
    /* x0 += 0 */ x1 += K1 + 3u;
    TFR(17) TFR(29) TFR(16) TFR(24)
    x0 += K1; x1 += K2 + 4u;
    TFR(13) TFR(15) TFR(26) TFR(6)
    x0 += K2; x1 += 5u;              // + ks[0]
#undef TFR
    return x0 ^ x1;            // bits1 ^ bits2  (the 32-bit draw)
}

// jax.random.uniform bit manipulation: (bits>>9)|0x3f800000, minus 1.0
__device__ __forceinline__ float u01f(uint32_t b) {
    return __uint_as_float((b >> 9) | 0x3F800000u) - 1.0f;
}

__device__ __forceinline__ float gumbelf(uint32_t b) {
    float u = u01f(b);
    return -__logf(-__logf(u + 1e-20f) + 1e-20f);
}

__global__ __launch_bounds__(BLOCK, 4)
void pq_fused(const float* __restrict__ X, const float* __restrict__ C,
              float* __restrict__ out)
{
    // LDS: 67584 + 4096 + 32768 = 104448 B -> 1 block/CU, 16 waves/CU
    __shared__ float CL[2][NW * LDC];   // C slices for books (pair, pair+4), padded
    __shared__ float XL[WPB][2][LW];    // per-wave x slices
    __shared__ float SPL[WPB][2][NW];   // per-wave soft_prob row (for Q phase)

    const int t    = threadIdx.x;
    const int wv   = t >> 6;
    const int lane = t & 63;
    const int pair = blockIdx.x & 3;    // books (pair, pair+4)
    const int rowblk = blockIdx.x >> 2; // 0..63, 512 rows each

    // ---- stage C (coalesced, one-time) ----
    for (int i = t; i < 2 * NW * LW; i += BLOCK) {
        int s = i >> 13;        // which book of the pair
        int r = i & 8191;
        int m = r >> 5;
        int l = r & 31;
        CL[s][m * LDC + l] = C[m * 256 + (pair + s * 4) * 32 + l];
    }
    __syncthreads();

    // ---- per-lane ||c||^2 for its 4 m's per book (registers) ----
    float c20[4], c21[4];
#pragma unroll
    for (int k = 0; k < 4; ++k) {
        const int m = (k << 6) + lane;
        float a0 = 0.f, a1 = 0.f;
#pragma unroll
        for (int l = 0; l < LW; ++l) {
            float v0 = CL[0][m * LDC + l];
            float v1 = CL[1][m * LDC + l];
            a0 = fmaf(v0, v0, a0);
            a1 = fmaf(v1, v1, a1);
        }
        c20[k] = a0; c21[k] = a1;
    }

    float* __restrict__ Qout = out;
    float* __restrict__ SP   = out + QSIZE;

    const int s_half = lane >> 5;   // 0: book pair, 1: book pair+4
    const int l_half = lane & 31;

    // one wave = one row per iteration; 32 iterations -> 512 rows per block
    for (int it = 0; it < 32; ++it) {
        const int n = (rowblk << 9) + (it << 4) + wv;

        // ---- load x slices (two 128B segments) ----
        float xv = X[n * 256 + (pair + s_half * 4) * 32 + l_half];
        XL[wv][s_half][l_half] = xv;

        // ---- ||x||^2 per book via shfl butterfly over 32-lane halves ----
        float sq = xv * xv;
#pragma unroll
        for (int msk = 1; msk < 32; msk <<= 1)
            sq += __shfl_xor(sq, msk, 64);
        float oth = __shfl_xor(sq, 32, 64);
        float x2a = (s_half == 0) ? sq : oth;
        float x2b = (s_half == 0) ? oth : sq;

        // ---- logits: lane owns m = k*64+lane for both books ----
        float la[4] = {0.f, 0.f, 0.f, 0.f};
        float lb[4] = {0.f, 0.f, 0.f, 0.f};
#pragma unroll
        for (int l = 0; l < LW; ++l) {
            float xa = XL[wv][0][l];    // broadcast reads (conflict-free)
            float xb = XL[wv][1][l];
#pragma unroll
            for (int k = 0; k < 4; ++k) {
                const int m = (k << 6) + lane;
                la[k] = fmaf(xa, CL[0][m * LDC + l], la[k]);
                lb[k] = fmaf(xb, CL[1][m * LDC + l], lb[k]);
            }
        }
#pragma unroll
        for (int k = 0; k < 4; ++k) {
            la[k] = 2.f * la[k] - x2a - c20[k];
            lb[k] = 2.f * lb[k] - x2b - c21[k];
        }

        // ---- softmax #1 over m (wave-wide reductions) ----
        float mxa = fmaxf(fmaxf(la[0], la[1]), fmaxf(la[2], la[3]));
        float mxb = fmaxf(fmaxf(lb[0], lb[1]), fmaxf(lb[2], lb[3]));
#pragma unroll
        for (int msk = 1; msk < 64; msk <<= 1) {
            mxa = fmaxf(mxa, __shfl_xor(mxa, msk, 64));
            mxb = fmaxf(mxb, __shfl_xor(mxb, msk, 64));
        }
        float ea[4], eb[4], sa = 0.f, sb = 0.f;
#pragma unroll
        for (int k = 0; k < 4; ++k) {
            ea[k] = __expf(la[k] - mxa); sa += ea[k];
            eb[k] = __expf(lb[k] - mxb); sb += eb[k];
        }
#pragma unroll
        for (int msk = 1; msk < 64; msk <<= 1) {
            sa += __shfl_xor(sa, msk, 64);
            sb += __shfl_xor(sb, msk, 64);
        }
        const float rsa = 1.0f / sa, rsb = 1.0f / sb;

        // ---- logp + gumbel -> z (partitionable threefry: 1 eval per element) ----
        const uint32_t jrow = (uint32_t)pair * (uint32_t)NMQ
                            + (uint32_t)n * 256u + (uint32_t)lane;
#pragma unroll
        for (int k = 0; k < 4; ++k) {
            uint32_t r0 = tfp32(jrow + (uint32_t)(k << 6));          // book pair
            uint32_t r1 = tfp32(jrow + (uint32_t)(k << 6) + HALFC);  // book pair+4
            float p0 = ea[k] * rsa;
            float p1 = eb[k] * rsb;
            la[k] = (__logf(p0 + 1e-9f) + gumbelf(r0)) * 2.0f;  // /GUMBEL_TEMP
            lb[k] = (__logf(p1 + 1e-9f) + gumbelf(r1)) * 2.0f;
        }

        // ---- softmax #2 ----
        mxa = fmaxf(fmaxf(la[0], la[1]), fmaxf(la[2], la[3]));
        mxb = fmaxf(fmaxf(lb[0], lb[1]), fmaxf(lb[2], lb[3]));
#pragma unroll
        for (int msk = 1; msk < 64; msk <<= 1) {
            mxa = fmaxf(mxa, __shfl_xor(mxa, msk, 64));
            mxb = fmaxf(mxb, __shfl_xor(mxb, msk, 64));
        }
        sa = 0.f; sb = 0.f;
#pragma unroll
        for (int k = 0; k < 4; ++k) {
            ea[k] = __expf(la[k] - mxa); sa += ea[k];
            eb[k] = __expf(lb[k] - mxb); sb += eb[k];
        }
#pragma unroll
        for (int msk = 1; msk < 64; msk <<= 1) {
            sa += __shfl_xor(sa, msk, 64);
            sb += __shfl_xor(sb, msk, 64);
        }
        const float ra2 = 1.0f / sa, rb2 = 1.0f / sb;

        // ---- write soft_prob (coalesced 256B per k per book) + stash in LDS ----
        float* __restrict__ sp0 = SP + (size_t)pair * NMQ + (size_t)n * 256;
        float* __restrict__ sp1 = sp0 + (size_t)4 * NMQ;
#pragma unroll
        for (int k = 0; k < 4; ++k) {
            const int m = (k << 6) + lane;
            float v0 = ea[k] * ra2;
            float v1 = eb[k] * rb2;
            sp0[m] = v0;
            sp1[m] = v1;
            SPL[wv][0][m] = v0;
            SPL[wv][1][m] = v1;
        }
        // wave-private LDS: per-wave DS ops execute in order; no block barrier needed

        // ---- Q: lane (s_half, l_half) accumulates over all 256 m ----
        {
            float q0 = 0.f, q1 = 0.f, q2 = 0.f, q3 = 0.f;
#pragma unroll 8
            for (int m = 0; m < NW; m += 4) {
                q0 = fmaf(SPL[wv][s_half][m + 0], CL[s_half][(m + 0) * LDC + l_half], q0);
                q1 = fmaf(SPL[wv][s_half][m + 1], CL[s_half][(m + 1) * LDC + l_half], q1);
                q2 = fmaf(SPL[wv][s_half][m + 2], CL[s_half][(m + 2) * LDC + l_half], q2);
                q3 = fmaf(SPL[wv][s_half][m + 3], CL[s_half][(m + 3) * LDC + l_half], q3);
            }
            Qout[(size_t)n * 256 + (pair + s_half * 4) * 32 + l_half] =
                (q0 + q1) + (q2 + q3);
        }
    }
}

extern "C" void kernel_launch(void* const* d_in, const int* in_sizes, int n_in,
                              void* d_out, int out_size, void* d_ws, size_t ws_size,
                              hipStream_t stream) {
    const float* X = (const float*)d_in[0];
    const float* C = (const float*)d_in[1];
    float* out = (float*)d_out;

    dim3 grid(256);   // 4 book-pairs x 64 row-blocks (512 rows each)
    dim3 block(BLOCK);
    hipLaunchKernelGGL(pq_fused, grid, block, 0, stream, X, C, out);
}

// Round 4
// 443.165 us; speedup vs baseline: 2.4276x; 2.4276x over previous
//
#include <hip/hip_runtime.h>
#include <stdint.h>

// Problem constants
#define NROWS 32768
#define NW    256                 // N_WORDS
#define NMQ   (NROWS * NW)        // per-book soft_prob elements
#define QSIZE (NROWS * 256)
#define LDCL  36                  // CL leading dim (16B-aligned rows, conflict-free f4)
#define WPB   16                  // waves per block

__device__ __forceinline__ uint32_t rotl32(uint32_t x, unsigned r) {
    return (x << r) | (x >> (32u - r));
}

// JAX partitionable threefry: bits[i] = x0^x1 of threefry2x32((0,42),(0,i)).
// Verified exact in round 3.
__device__ __forceinline__ uint32_t tfp32(uint32_t idx) {
    const uint32_t K1 = 42u;
    const uint32_t K2 = 0x1BD11BDAu ^ 42u;
    uint32_t x0 = 0u;
    uint32_t x1 = idx + K1;
#define TFR(r) { x0 += x1; x1 = rotl32(x1, (r)) ^ x0; }
    TFR(13) TFR(15) TFR(26) TFR(6)
    x0 += K1; x1 += K2 + 1u;
    TFR(17) TFR(29) TFR(16) TFR(24)
    x0 += K2; x1 += 2u;
    TFR(13) TFR(15) TFR(26) TFR(6)
    x1 += K1 + 3u;
    TFR(17) TFR(29) TFR(16) TFR(24)
    x0 += K1; x1 += K2 + 4u;
    TFR(13) TFR(15) TFR(26) TFR(6)
    x0 += K2; x1 += 5u;
#undef TFR
    return x0 ^ x1;
}

__device__ __forceinline__ float u01f(uint32_t b) {
    return __uint_as_float((b >> 9) | 0x3F800000u) - 1.0f;
}
__device__ __forceinline__ float gumbelf(uint32_t b) {
    float u = u01f(b);
    return -__logf(-__logf(u + 1e-20f) + 1e-20f);
}

// DPP-based 64-lane reductions (VALU pipe, zero LDS traffic).
#define DPPF(oldv, x, ctrl) \
    __int_as_float(__builtin_amdgcn_update_dpp(__float_as_int(oldv), \
        __float_as_int(x), (ctrl), 0xf, 0xf, false))

__device__ __forceinline__ float wave_max(float x) {
    x = fmaxf(x, DPPF(-3.4e38f, x, 0x111));   // row_shr:1
    x = fmaxf(x, DPPF(-3.4e38f, x, 0x112));   // row_shr:2
    x = fmaxf(x, DPPF(-3.4e38f, x, 0x114));   // row_shr:4
    x = fmaxf(x, DPPF(-3.4e38f, x, 0x118));   // row_shr:8
    x = fmaxf(x, DPPF(-3.4e38f, x, 0x142));   // row_bcast15
    x = fmaxf(x, DPPF(-3.4e38f, x, 0x143));   // row_bcast31
    return __int_as_float(__builtin_amdgcn_readlane(__float_as_int(x), 63));
}
__device__ __forceinline__ float wave_sum(float x) {
    x += DPPF(0.0f, x, 0x111);
    x += DPPF(0.0f, x, 0x112);
    x += DPPF(0.0f, x, 0x114);
    x += DPPF(0.0f, x, 0x118);
    x += DPPF(0.0f, x, 0x142);
    x += DPPF(0.0f, x, 0x143);
    return __int_as_float(__builtin_amdgcn_readlane(__float_as_int(x), 63));
}

__global__ __launch_bounds__(1024, 1)
void pq_fused(const float* __restrict__ X, const float* __restrict__ C,
              float* __restrict__ out)
{
    // LDS: 36864 + 32768 + 8192 + 65536 = 143360 B -> 1 block/CU, 16 waves
    __shared__ float CL[NW * LDCL];      // C[m][l], row-major, LDC=36
    __shared__ float CT[32 * NW];        // C[l][m], f4-group XOR-swizzled
    __shared__ float XL[WPB][4][32];     // per-wave x rows
    __shared__ float SPB[WPB][4][NW];    // per-wave soft_prob rows (f32)

    const int t    = threadIdx.x;
    const int wv   = t >> 6;
    const int lane = t & 63;
    const int b      = blockIdx.x & 7;   // book
    const int rowblk = blockIdx.x >> 3;  // 0..63, 512 rows each

    // ---- stage C into CL (row-major) and CT (transposed, swizzled) ----
    for (int i = t; i < 8192; i += 1024) {
        int m = i >> 5, l = i & 31;
        float v = C[m * 256 + b * 32 + l];
        CL[m * LDCL + l] = v;
        int g = m >> 2;
        CT[l * NW + ((g ^ ((l & 7) << 3)) << 2) + (m & 3)] = v;
    }
    __syncthreads();

    // ---- ||c||^2 for lane's 4 m's ----
    float c2[4];
#pragma unroll
    for (int k = 0; k < 4; ++k) {
        const int m = (k << 6) + lane;
        float a = 0.f;
#pragma unroll
        for (int lg = 0; lg < 8; ++lg) {
            float4 c4 = *reinterpret_cast<const float4*>(&CL[m * LDCL + lg * 4]);
            a = fmaf(c4.x, c4.x, fmaf(c4.y, c4.y, fmaf(c4.z, c4.z, fmaf(c4.w, c4.w, a))));
        }
        c2[k] = a;
    }

    float* __restrict__ Qout = out;
    float* __restrict__ SP   = out + QSIZE;
    const float2* __restrict__ X2 = reinterpret_cast<const float2*>(X);

    // 8 iterations x (16 waves x 4 rows) = 512 rows per block
    for (int it = 0; it < 8; ++it) {
        const int r0 = (rowblk << 9) + (it << 6) + (wv << 2);

        // ---- stage this wave's 4 x-rows into XL (1 global float2/lane) ----
        {
            const int rr = lane >> 4, f2 = lane & 15;
            float2 xv = X2[(size_t)(r0 + rr) * 128 + b * 16 + f2];
            *reinterpret_cast<float2*>(&XL[wv][rr][f2 * 2]) = xv;
        }

        // ---- logits: la[r][k] = dot(x_r, c_m), m = k*64+lane ----
        float la[4][4];
#pragma unroll
        for (int r = 0; r < 4; ++r)
#pragma unroll
            for (int k = 0; k < 4; ++k) la[r][k] = 0.f;

#pragma unroll
        for (int lg = 0; lg < 8; ++lg) {
            float4 c40 = *reinterpret_cast<const float4*>(&CL[(0 * 64 + lane) * LDCL + lg * 4]);
            float4 c41 = *reinterpret_cast<const float4*>(&CL[(1 * 64 + lane) * LDCL + lg * 4]);
            float4 c42 = *reinterpret_cast<const float4*>(&CL[(2 * 64 + lane) * LDCL + lg * 4]);
            float4 c43 = *reinterpret_cast<const float4*>(&CL[(3 * 64 + lane) * LDCL + lg * 4]);
#pragma unroll
            for (int r = 0; r < 4; ++r) {
                float4 x4 = *reinterpret_cast<const float4*>(&XL[wv][r][lg * 4]);
                la[r][0] = fmaf(x4.x, c40.x, fmaf(x4.y, c40.y, fmaf(x4.z, c40.z, fmaf(x4.w, c40.w, la[r][0]))));
                la[r][1] = fmaf(x4.x, c41.x, fmaf(x4.y, c41.y, fmaf(x4.z, c41.z, fmaf(x4.w, c41.w, la[r][1]))));
                la[r][2] = fmaf(x4.x, c42.x, fmaf(x4.y, c42.y, fmaf(x4.z, c42.z, fmaf(x4.w, c42.w, la[r][2]))));
                la[r][3] = fmaf(x4.x, c43.x, fmaf(x4.y, c43.y, fmaf(x4.z, c43.z, fmaf(x4.w, c43.w, la[r][3]))));
            }
        }

        // ---- per-row: softmax1 -> logp+gumbel -> softmax2 -> stores ----
        // note: -||x||^2 is a per-row constant -> softmax-invariant -> dropped
#pragma unroll
        for (int r = 0; r < 4; ++r) {
            const int n = r0 + r;
            float l0 = 2.f * la[r][0] - c2[0];
            float l1 = 2.f * la[r][1] - c2[1];
            float l2 = 2.f * la[r][2] - c2[2];
            float l3 = 2.f * la[r][3] - c2[3];

            float mx = wave_max(fmaxf(fmaxf(l0, l1), fmaxf(l2, l3)));
            float e0 = __expf(l0 - mx), e1 = __expf(l1 - mx);
            float e2 = __expf(l2 - mx), e3 = __expf(l3 - mx);
            float s  = wave_sum((e0 + e1) + (e2 + e3));
            float rs = __builtin_amdgcn_rcpf(s);

            const uint32_t base = (uint32_t)b * (uint32_t)NMQ + (uint32_t)n * 256u + (uint32_t)lane;
            float z0 = (__logf(e0 * rs + 1e-9f) + gumbelf(tfp32(base       ))) * 2.0f;
            float z1 = (__logf(e1 * rs + 1e-9f) + gumbelf(tfp32(base +  64u))) * 2.0f;
            float z2 = (__logf(e2 * rs + 1e-9f) + gumbelf(tfp32(base + 128u))) * 2.0f;
            float z3 = (__logf(e3 * rs + 1e-9f) + gumbelf(tfp32(base + 192u))) * 2.0f;

            float mx2 = wave_max(fmaxf(fmaxf(z0, z1), fmaxf(z2, z3)));
            e0 = __expf(z0 - mx2); e1 = __expf(z1 - mx2);
            e2 = __expf(z2 - mx2); e3 = __expf(z3 - mx2);
            float s2  = wave_sum((e0 + e1) + (e2 + e3));
            float rs2 = __builtin_amdgcn_rcpf(s2);

            float p0 = e0 * rs2, p1 = e1 * rs2, p2 = e2 * rs2, p3 = e3 * rs2;

            float* spg = SP + (size_t)b * NMQ + (size_t)n * 256 + lane;
            spg[0]   = p0; spg[64]  = p1; spg[128] = p2; spg[192] = p3;
            SPB[wv][r][lane]       = p0;
            SPB[wv][r][64 + lane]  = p1;
            SPB[wv][r][128 + lane] = p2;
            SPB[wv][r][192 + lane] = p3;
        }
        // wave-private LDS (SPB/XL): per-wave DS ops are in-order; no barrier

        // ---- Q: lane (rh, lq) handles rows {rh, rh+2}, col lq ----
        {
            const int lq = lane & 31, rh = lane >> 5;
            const int swz = (lq & 7) << 3;
            const float4* CT4 = reinterpret_cast<const float4*>(CT);
            const float4* S4a = reinterpret_cast<const float4*>(&SPB[wv][rh][0]);
            const float4* S4b = reinterpret_cast<const float4*>(&SPB[wv][rh + 2][0]);
            float q0 = 0.f, q1 = 0.f;
#pragma unroll
            for (int g8 = 0; g8 < 32; ++g8) {
                float4 ca = CT4[lq * 64 + ((2 * g8)     ^ swz)];
                float4 cb = CT4[lq * 64 + ((2 * g8 + 1) ^ swz)];
                float4 sa = S4a[2 * g8], sb = S4a[2 * g8 + 1];
                float4 ta = S4b[2 * g8], tb = S4b[2 * g8 + 1];
                q0 = fmaf(sa.x, ca.x, fmaf(sa.y, ca.y, fmaf(sa.z, ca.z, fmaf(sa.w, ca.w, q0))));
                q0 = fmaf(sb.x, cb.x, fmaf(sb.y, cb.y, fmaf(sb.z, cb.z, fmaf(sb.w, cb.w, q0))));
                q1 = fmaf(ta.x, ca.x, fmaf(ta.y, ca.y, fmaf(ta.z, ca.z, fmaf(ta.w, ca.w, q1))));
                q1 = fmaf(tb.x, cb.x, fmaf(tb.y, cb.y, fmaf(tb.z, cb.z, fmaf(tb.w, cb.w, q1))));
            }
            Qout[(size_t)(r0 + rh)     * 256 + b * 32 + lq] = q0;
            Qout[(size_t)(r0 + rh + 2) * 256 + b * 32 + lq] = q1;
        }
    }
}

extern "C" void kernel_launch(void* const* d_in, const int* in_sizes, int n_in,
                              void* d_out, int out_size, void* d_ws, size_t ws_size,
                              hipStream_t stream) {
    const float* X = (const float*)d_in[0];
    const float* C = (const float*)d_in[1];
    float* out = (float*)d_out;

    dim3 grid(512);   // 8 books x 64 row-blocks (512 rows each)
    dim3 block(1024);
    hipLaunchKernelGGL(pq_fused, grid, block, 0, stream, X, C, out);
}

// Round 6
// 393.108 us; speedup vs baseline: 2.7367x; 1.1273x over previous
//
#include <hip/hip_runtime.h>
#include <stdint.h>

// Problem constants
#define NROWS 32768
#define NW    256                 // N_WORDS
#define NMQ   (NROWS * NW)        // per-book soft_prob elements
#define QSIZE (NROWS * 256)
#define LDCL  36                  // CL leading dim (8-lane-group conflict-free f4 reads)
#define WPB   16                  // waves per block

__device__ __forceinline__ uint32_t rotl32(uint32_t x, unsigned r) {
    return (x << r) | (x >> (32u - r));
}

// JAX partitionable threefry: bits[i] = x0^x1 of threefry2x32((0,42),(0,i)).
// Verified exact in rounds 3-4.
__device__ __forceinline__ uint32_t tfp32(uint32_t idx) {
    const uint32_t K1 = 42u;
    const uint32_t K2 = 0x1BD11BDAu ^ 42u;
    uint32_t x0 = 0u;
    uint32_t x1 = idx + K1;
#define TFR(r) { x0 += x1; x1 = rotl32(x1, (r)) ^ x0; }
    TFR(13) TFR(15) TFR(26) TFR(6)
    x0 += K1; x1 += K2 + 1u;
    TFR(17) TFR(29) TFR(16) TFR(24)
    x0 += K2; x1 += 2u;
    TFR(13) TFR(15) TFR(26) TFR(6)
    x1 += K1 + 3u;
    TFR(17) TFR(29) TFR(16) TFR(24)
    x0 += K1; x1 += K2 + 4u;
    TFR(13) TFR(15) TFR(26) TFR(6)
    x0 += K2; x1 += 5u;
#undef TFR
    return x0 ^ x1;
}

__device__ __forceinline__ float u01f(uint32_t b) {
    return __uint_as_float((b >> 9) | 0x3F800000u) - 1.0f;
}
__device__ __forceinline__ float gumbelf(uint32_t b) {
    float u = u01f(b);
    return -__logf(-__logf(u + 1e-20f) + 1e-20f);
}

// DPP-based 64-lane reductions (VALU pipe, zero LDS traffic).
#define DPPF(oldv, x, ctrl) \
    __int_as_float(__builtin_amdgcn_update_dpp(__float_as_int(oldv), \
        __float_as_int(x), (ctrl), 0xf, 0xf, false))

__device__ __forceinline__ float wave_max(float x) {
    x = fmaxf(x, DPPF(-3.4e38f, x, 0x111));   // row_shr:1
    x = fmaxf(x, DPPF(-3.4e38f, x, 0x112));   // row_shr:2
    x = fmaxf(x, DPPF(-3.4e38f, x, 0x114));   // row_shr:4
    x = fmaxf(x, DPPF(-3.4e38f, x, 0x118));   // row_shr:8
    x = fmaxf(x, DPPF(-3.4e38f, x, 0x142));   // row_bcast15
    x = fmaxf(x, DPPF(-3.4e38f, x, 0x143));   // row_bcast31
    return __int_as_float(__builtin_amdgcn_readlane(__float_as_int(x), 63));
}
__device__ __forceinline__ float wave_sum(float x) {
    x += DPPF(0.0f, x, 0x111);
    x += DPPF(0.0f, x, 0x112);
    x += DPPF(0.0f, x, 0x114);
    x += DPPF(0.0f, x, 0x118);
    x += DPPF(0.0f, x, 0x142);
    x += DPPF(0.0f, x, 0x143);
    return __int_as_float(__builtin_amdgcn_readlane(__float_as_int(x), 63));
}

__global__
__attribute__((amdgpu_flat_work_group_size(1024, 1024), amdgpu_waves_per_eu(4, 4)))
void pq_fused(const float* __restrict__ X, const float* __restrict__ C,
              float* __restrict__ out)
{
    // LDS: 36864 + 32768 + 8192 + 65536 = 143360 B -> 1 block/CU, 16 waves
    __shared__ float CL[NW * LDCL];      // 2*C[m][l], row-major, LDC=36
    __shared__ float CT[32 * NW];        // C[l][m], f4-group XOR-swizzled (low 3 bits)
    __shared__ float XL[WPB][4][32];     // per-wave x rows
    __shared__ float SPB[WPB][4][NW];    // per-wave soft_prob rows (f32, linear)

    const int t    = threadIdx.x;
    const int wv   = t >> 6;
    const int lane = t & 63;
    const int b      = blockIdx.x & 7;   // book
    const int rowblk = blockIdx.x >> 3;  // 0..63, 512 rows each

    // ---- stage C: CL holds 2*c (folds logits 2x); CT holds c transposed+swizzled ----
    for (int i = t; i < 8192; i += 1024) {
        int m = i >> 5, l = i & 31;
        float v = C[m * 256 + b * 32 + l];
        CL[m * LDCL + l] = 2.0f * v;
        int g = m >> 2;
        CT[l * NW + ((g ^ (l & 7)) << 2) + (m & 3)] = v;   // swizzle LOW 3 bits of f4-group
    }
    __syncthreads();

    // ---- ||c||^2 for lane's 4 m's (from 2c: scale by 0.25) ----
    float c2[4];
#pragma unroll
    for (int k = 0; k < 4; ++k) {
        const int m = (k << 6) + lane;
        float a = 0.f;
#pragma unroll
        for (int lg = 0; lg < 8; ++lg) {
            float4 c4 = *reinterpret_cast<const float4*>(&CL[m * LDCL + lg * 4]);
            a = fmaf(c4.x, c4.x, fmaf(c4.y, c4.y, fmaf(c4.z, c4.z, fmaf(c4.w, c4.w, a))));
        }
        c2[k] = 0.25f * a;
    }

    float* __restrict__ Qout = out;
    float* __restrict__ SP   = out + QSIZE;
    const float2* __restrict__ X2 = reinterpret_cast<const float2*>(X);

    // 8 iterations x (16 waves x 4 rows) = 512 rows per block
    for (int it = 0; it < 8; ++it) {
        const int r0 = (rowblk << 9) + (it << 6) + (wv << 2);

        // ---- stage this wave's 4 x-rows into XL (1 global float2/lane) ----
        {
            const int rr = lane >> 4, f2 = lane & 15;
            float2 xv = X2[(size_t)(r0 + rr) * 128 + b * 16 + f2];
            *reinterpret_cast<float2*>(&XL[wv][rr][f2 * 2]) = xv;
        }

        // ---- logits: la[r][k] = dot(x_r, 2*c_m), m = k*64+lane ----
        float la[4][4];
#pragma unroll
        for (int r = 0; r < 4; ++r)
#pragma unroll
            for (int k = 0; k < 4; ++k) la[r][k] = 0.f;

#pragma unroll
        for (int lg = 0; lg < 8; ++lg) {
            float4 c40 = *reinterpret_cast<const float4*>(&CL[(0 * 64 + lane) * LDCL + lg * 4]);
            float4 c41 = *reinterpret_cast<const float4*>(&CL[(1 * 64 + lane) * LDCL + lg * 4]);
            float4 c42 = *reinterpret_cast<const float4*>(&CL[(2 * 64 + lane) * LDCL + lg * 4]);
            float4 c43 = *reinterpret_cast<const float4*>(&CL[(3 * 64 + lane) * LDCL + lg * 4]);
#pragma unroll
            for (int r = 0; r < 4; ++r) {
                float4 x4 = *reinterpret_cast<const float4*>(&XL[wv][r][lg * 4]);
                la[r][0] = fmaf(x4.x, c40.x, fmaf(x4.y, c40.y, fmaf(x4.z, c40.z, fmaf(x4.w, c40.w, la[r][0]))));
                la[r][1] = fmaf(x4.x, c41.x, fmaf(x4.y, c41.y, fmaf(x4.z, c41.z, fmaf(x4.w, c41.w, la[r][1]))));
                la[r][2] = fmaf(x4.x, c42.x, fmaf(x4.y, c42.y, fmaf(x4.z, c42.z, fmaf(x4.w, c42.w, la[r][2]))));
                la[r][3] = fmaf(x4.x, c43.x, fmaf(x4.y, c43.y, fmaf(x4.z, c43.z, fmaf(x4.w, c43.w, la[r][3]))));
            }
        }

        // ---- per-row: softmax1 -> logp+gumbel -> softmax2 -> stores ----
        // note: -||x||^2 is a per-row constant -> softmax-invariant -> dropped
#pragma unroll
        for (int r = 0; r < 4; ++r) {
            const int n = r0 + r;
            float l0 = la[r][0] - c2[0];
            float l1 = la[r][1] - c2[1];
            float l2 = la[r][2] - c2[2];
            float l3 = la[r][3] - c2[3];

            float mx = wave_max(fmaxf(fmaxf(l0, l1), fmaxf(l2, l3)));
            float e0 = __expf(l0 - mx), e1 = __expf(l1 - mx);
            float e2 = __expf(l2 - mx), e3 = __expf(l3 - mx);
            float s  = wave_sum((e0 + e1) + (e2 + e3));
            float rs = __builtin_amdgcn_rcpf(s);

            const uint32_t base = (uint32_t)b * (uint32_t)NMQ + (uint32_t)n * 256u + (uint32_t)lane;
            float z0 = (__logf(e0 * rs + 1e-9f) + gumbelf(tfp32(base       ))) * 2.0f;
            float z1 = (__logf(e1 * rs + 1e-9f) + gumbelf(tfp32(base +  64u))) * 2.0f;
            float z2 = (__logf(e2 * rs + 1e-9f) + gumbelf(tfp32(base + 128u))) * 2.0f;
            float z3 = (__logf(e3 * rs + 1e-9f) + gumbelf(tfp32(base + 192u))) * 2.0f;

            float mx2 = wave_max(fmaxf(fmaxf(z0, z1), fmaxf(z2, z3)));
            e0 = __expf(z0 - mx2); e1 = __expf(z1 - mx2);
            e2 = __expf(z2 - mx2); e3 = __expf(z3 - mx2);
            float s2  = wave_sum((e0 + e1) + (e2 + e3));
            float rs2 = __builtin_amdgcn_rcpf(s2);

            float p0 = e0 * rs2, p1 = e1 * rs2, p2 = e2 * rs2, p3 = e3 * rs2;

            float* spg = SP + (size_t)b * NMQ + (size_t)n * 256 + lane;
            spg[0]   = p0; spg[64]  = p1; spg[128] = p2; spg[192] = p3;
            SPB[wv][r][lane]       = p0;
            SPB[wv][r][64 + lane]  = p1;
            SPB[wv][r][128 + lane] = p2;
            SPB[wv][r][192 + lane] = p3;
        }
        // wave-private LDS (SPB/XL): per-wave DS ops are in-order; no barrier

        // ---- Q: lane (rh, lq) handles rows {rh, rh+2}, col lq ----
        // CT is read with the XOR (slot s holds c-group s^swz); SPB is linear.
        {
            const int lq = lane & 31, rh = lane >> 5;
            const int swz = lq & 7;
            const float4* CT4 = reinterpret_cast<const float4*>(CT);
            const float4* S4a = reinterpret_cast<const float4*>(&SPB[wv][rh][0]);
            const float4* S4b = reinterpret_cast<const float4*>(&SPB[wv][rh + 2][0]);
            float q0 = 0.f, q1 = 0.f;
#pragma unroll
            for (int g8 = 0; g8 < 32; ++g8) {
                float4 ca = CT4[lq * 64 + ((2 * g8)     ^ swz)];   // c-group 2g8
                float4 cb = CT4[lq * 64 + ((2 * g8 + 1) ^ swz)];   // c-group 2g8+1
                float4 sa = S4a[2 * g8], sb = S4a[2 * g8 + 1];     // sp groups (linear!)
                float4 ta = S4b[2 * g8], tb = S4b[2 * g8 + 1];
                q0 = fmaf(sa.x, ca.x, fmaf(sa.y, ca.y, fmaf(sa.z, ca.z, fmaf(sa.w, ca.w, q0))));
                q0 = fmaf(sb.x, cb.x, fmaf(sb.y, cb.y, fmaf(sb.z, cb.z, fmaf(sb.w, cb.w, q0))));
                q1 = fmaf(ta.x, ca.x, fmaf(ta.y, ca.y, fmaf(ta.z, ca.z, fmaf(ta.w, ca.w, q1))));
                q1 = fmaf(tb.x, cb.x, fmaf(tb.y, cb.y, fmaf(tb.z, cb.z, fmaf(tb.w, cb.w, q1))));
            }
            Qout[(size_t)(r0 + rh)     * 256 + b * 32 + lq] = q0;
            Qout[(size_t)(r0 + rh + 2) * 256 + b * 32 + lq] = q1;
        }
    }
}

extern "C" void kernel_launch(void* const* d_in, const int* in_sizes, int n_in,
                              void* d_out, int out_size, void* d_ws, size_t ws_size,
                              hipStream_t stream) {
    const float* X = (const float*)d_in[0];
    const float* C = (const float*)d_in[1];
    float* out = (float*)d_out;

    dim3 grid(512);   // 8 books x 64 row-blocks (512 rows each)
    dim3 block(1024);
    hipLaunchKernelGGL(pq_fused, grid, block, 0, stream, X, C, out);
}

// Round 7
// 346.650 us; speedup vs baseline: 3.1035x; 1.1340x over previous
//
#include <hip/hip_runtime.h>
#include <stdint.h>

// Problem constants
#define NROWS 32768
#define NW    256                 // N_WORDS
#define NMQ   (NROWS * NW)        // per-book soft_prob elements
#define QSIZE (NROWS * 256)
#define LDCL  36                  // CL leading dim (8-lane-group conflict-free f4 reads)
#define WPB   16                  // waves per block

// JAX partitionable threefry: bits[i] = x0^x1 of threefry2x32((0,42),(0,i)).
// Verified exact in rounds 3-6. rotl via builtin -> guaranteed v_alignbit_b32.
__device__ __forceinline__ uint32_t tfp32(uint32_t idx) {
    const uint32_t K1 = 42u;
    const uint32_t K2 = 0x1BD11BDAu ^ 42u;
    uint32_t x0 = 0u;
    uint32_t x1 = idx + K1;
#define TFR(r) { x0 += x1; x1 = __builtin_rotateleft32(x1, (r)) ^ x0; }
    TFR(13) TFR(15) TFR(26) TFR(6)
    x0 += K1; x1 += K2 + 1u;
    TFR(17) TFR(29) TFR(16) TFR(24)
    x0 += K2; x1 += 2u;
    TFR(13) TFR(15) TFR(26) TFR(6)
    x1 += K1 + 3u;
    TFR(17) TFR(29) TFR(16) TFR(24)
    x0 += K1; x1 += K2 + 4u;
    TFR(13) TFR(15) TFR(26) TFR(6)
    x0 += K2; x1 += 5u;
#undef TFR
    return x0 ^ x1;
}

__device__ __forceinline__ float u01f(uint32_t b) {
    return __uint_as_float((b >> 9) | 0x3F800000u) - 1.0f;
}
// gumbel: g = -log(-log(u+1e-20)+1e-20)
__device__ __forceinline__ float gumbelf(uint32_t b) {
    float w = -__logf(u01f(b) + 1e-20f) + 1e-20f;
    return -__logf(w);
}

// DPP-based 64-lane reductions (VALU pipe, zero LDS traffic).
#define DPPF(oldv, x, ctrl) \
    __int_as_float(__builtin_amdgcn_update_dpp(__float_as_int(oldv), \
        __float_as_int(x), (ctrl), 0xf, 0xf, false))

__device__ __forceinline__ float wave_max(float x) {
    x = fmaxf(x, DPPF(-3.4e38f, x, 0x111));   // row_shr:1
    x = fmaxf(x, DPPF(-3.4e38f, x, 0x112));   // row_shr:2
    x = fmaxf(x, DPPF(-3.4e38f, x, 0x114));   // row_shr:4
    x = fmaxf(x, DPPF(-3.4e38f, x, 0x118));   // row_shr:8
    x = fmaxf(x, DPPF(-3.4e38f, x, 0x142));   // row_bcast15
    x = fmaxf(x, DPPF(-3.4e38f, x, 0x143));   // row_bcast31
    return __int_as_float(__builtin_amdgcn_readlane(__float_as_int(x), 63));
}
__device__ __forceinline__ float wave_sum(float x) {
    x += DPPF(0.0f, x, 0x111);
    x += DPPF(0.0f, x, 0x112);
    x += DPPF(0.0f, x, 0x114);
    x += DPPF(0.0f, x, 0x118);
    x += DPPF(0.0f, x, 0x142);
    x += DPPF(0.0f, x, 0x143);
    return __int_as_float(__builtin_amdgcn_readlane(__float_as_int(x), 63));
}

__global__ __launch_bounds__(1024)
void pq_fused(const float* __restrict__ X, const float* __restrict__ C,
              float* __restrict__ out)
{
    // LDS: 36864 + 33280 + 8192 + 65536 = 143872 B -> 1 block/CU, 16 waves
    __shared__ float  CL[NW * LDCL];     // 2*C[m][l], row-major, LDC=36
    __shared__ float4 CT4[32][65];       // C^T: CT4[l][g] = c[4g..4g+3][l], padded
    __shared__ float  XL[WPB][4][32];    // per-wave x rows
    __shared__ float  SPB[WPB][4][NW];   // per-wave soft_prob rows (f32, linear)

    const int t    = threadIdx.x;
    const int wv   = t >> 6;
    const int lane = t & 63;
    const int b      = blockIdx.x & 7;   // book
    const int rowblk = blockIdx.x >> 3;  // 0..63, 512 rows each

    // ---- stage C: CL holds 2*c (folds logits 2x); CT4 holds c transposed ----
    for (int i = t; i < 8192; i += 1024) {
        int m = i >> 5, l = i & 31;
        float v = C[m * 256 + b * 32 + l];
        CL[m * LDCL + l] = 2.0f * v;
        reinterpret_cast<float*>(&CT4[l][m >> 2])[m & 3] = v;
    }
    __syncthreads();

    // ---- ||c||^2 for lane's 4 m's (from 2c: scale by 0.25) ----
    float c2[4];
#pragma unroll
    for (int k = 0; k < 4; ++k) {
        const int m = (k << 6) + lane;
        float a = 0.f;
#pragma unroll
        for (int lg = 0; lg < 8; ++lg) {
            float4 c4 = *reinterpret_cast<const float4*>(&CL[m * LDCL + lg * 4]);
            a = fmaf(c4.x, c4.x, fmaf(c4.y, c4.y, fmaf(c4.z, c4.z, fmaf(c4.w, c4.w, a))));
        }
        c2[k] = 0.25f * a;
    }

    float* __restrict__ Qout = out;
    float* __restrict__ SP   = out + QSIZE;
    const float2* __restrict__ X2 = reinterpret_cast<const float2*>(X);

    // 8 iterations x (16 waves x 4 rows) = 512 rows per block
    for (int it = 0; it < 8; ++it) {
        const int r0 = (rowblk << 9) + (it << 6) + (wv << 2);

        // ---- stage this wave's 4 x-rows into XL (1 global float2/lane) ----
        {
            const int rr = lane >> 4, f2 = lane & 15;
            float2 xv = X2[(size_t)(r0 + rr) * 128 + b * 16 + f2];
            *reinterpret_cast<float2*>(&XL[wv][rr][f2 * 2]) = xv;
        }

        // ---- logits: la[r][k] = dot(x_r, 2*c_m), m = k*64+lane ----
        float la[4][4];
#pragma unroll
        for (int r = 0; r < 4; ++r)
#pragma unroll
            for (int k = 0; k < 4; ++k) la[r][k] = 0.f;

#pragma unroll
        for (int lg = 0; lg < 8; ++lg) {
            float4 c40 = *reinterpret_cast<const float4*>(&CL[(0 * 64 + lane) * LDCL + lg * 4]);
            float4 c41 = *reinterpret_cast<const float4*>(&CL[(1 * 64 + lane) * LDCL + lg * 4]);
            float4 c42 = *reinterpret_cast<const float4*>(&CL[(2 * 64 + lane) * LDCL + lg * 4]);
            float4 c43 = *reinterpret_cast<const float4*>(&CL[(3 * 64 + lane) * LDCL + lg * 4]);
#pragma unroll
            for (int r = 0; r < 4; ++r) {
                float4 x4 = *reinterpret_cast<const float4*>(&XL[wv][r][lg * 4]);
                la[r][0] = fmaf(x4.x, c40.x, fmaf(x4.y, c40.y, fmaf(x4.z, c40.z, fmaf(x4.w, c40.w, la[r][0]))));
                la[r][1] = fmaf(x4.x, c41.x, fmaf(x4.y, c41.y, fmaf(x4.z, c41.z, fmaf(x4.w, c41.w, la[r][1]))));
                la[r][2] = fmaf(x4.x, c42.x, fmaf(x4.y, c42.y, fmaf(x4.z, c42.z, fmaf(x4.w, c42.w, la[r][2]))));
                la[r][3] = fmaf(x4.x, c43.x, fmaf(x4.y, c43.y, fmaf(x4.z, c43.z, fmaf(x4.w, c43.w, la[r][3]))));
            }
        }

        // ---- per-row: z = 2*(l + g) directly (softmax1 algebraically removed:
        //      softmax((log softmax(L) + g)/T) == softmax(2(L+g)) up to row const;
        //      the +1e-9 eps only perturbs terms with post-softmax weight <1e-5) ----
#pragma unroll
        for (int r = 0; r < 4; ++r) {
            const int n = r0 + r;
            const uint32_t base = (uint32_t)b * (uint32_t)NMQ + (uint32_t)n * 256u + (uint32_t)lane;

            float z0 = 2.0f * ((la[r][0] - c2[0]) + gumbelf(tfp32(base       )));
            float z1 = 2.0f * ((la[r][1] - c2[1]) + gumbelf(tfp32(base +  64u)));
            float z2 = 2.0f * ((la[r][2] - c2[2]) + gumbelf(tfp32(base + 128u)));
            float z3 = 2.0f * ((la[r][3] - c2[3]) + gumbelf(tfp32(base + 192u)));

            float mx = wave_max(fmaxf(fmaxf(z0, z1), fmaxf(z2, z3)));
            float e0 = __expf(z0 - mx), e1 = __expf(z1 - mx);
            float e2 = __expf(z2 - mx), e3 = __expf(z3 - mx);
            float s  = wave_sum((e0 + e1) + (e2 + e3));
            float rs = __builtin_amdgcn_rcpf(s);

            float p0 = e0 * rs, p1 = e1 * rs, p2 = e2 * rs, p3 = e3 * rs;

            float* spg = SP + (size_t)b * NMQ + (size_t)n * 256 + lane;
            spg[0]   = p0; spg[64]  = p1; spg[128] = p2; spg[192] = p3;
            SPB[wv][r][lane]       = p0;
            SPB[wv][r][64 + lane]  = p1;
            SPB[wv][r][128 + lane] = p2;
            SPB[wv][r][192 + lane] = p3;
        }
        // wave-private LDS (SPB/XL): per-wave DS ops are in-order; no barrier

        // ---- Q: lane (rh, lq) handles rows {rh, rh+2}, col lq ----
        // CT4 padded stride 65 -> conflict-free, immediate-offset addressing.
        {
            const int lq = lane & 31, rh = lane >> 5;
            const float4* Crow = &CT4[lq][0];
            const float4* S4a  = reinterpret_cast<const float4*>(&SPB[wv][rh][0]);
            const float4* S4b  = reinterpret_cast<const float4*>(&SPB[wv][rh + 2][0]);
            float q0 = 0.f, q1 = 0.f;
#pragma unroll
            for (int g8 = 0; g8 < 32; ++g8) {
                float4 ca = Crow[2 * g8];          // c[m=8g8..+3][lq]
                float4 cb = Crow[2 * g8 + 1];      // c[m=8g8+4..+7][lq]
                float4 sa = S4a[2 * g8], sb = S4a[2 * g8 + 1];
                float4 ta = S4b[2 * g8], tb = S4b[2 * g8 + 1];
                q0 = fmaf(sa.x, ca.x, fmaf(sa.y, ca.y, fmaf(sa.z, ca.z, fmaf(sa.w, ca.w, q0))));
                q0 = fmaf(sb.x, cb.x, fmaf(sb.y, cb.y, fmaf(sb.z, cb.z, fmaf(sb.w, cb.w, q0))));
                q1 = fmaf(ta.x, ca.x, fmaf(ta.y, ca.y, fmaf(ta.z, ca.z, fmaf(ta.w, ca.w, q1))));
                q1 = fmaf(tb.x, cb.x, fmaf(tb.y, cb.y, fmaf(tb.z, cb.z, fmaf(tb.w, cb.w, q1))));
            }
            Qout[(size_t)(r0 + rh)     * 256 + b * 32 + lq] = q0;
            Qout[(size_t)(r0 + rh + 2) * 256 + b * 32 + lq] = q1;
        }
    }
}

extern "C" void kernel_launch(void* const* d_in, const int* in_sizes, int n_in,
                              void* d_out, int out_size, void* d_ws, size_t ws_size,
                              hipStream_t stream) {
    const float* X = (const float*)d_in[0];
    const float* C = (const float*)d_in[1];
    float* out = (float*)d_out;

    dim3 grid(512);   // 8 books x 64 row-blocks (512 rows each)
    dim3 block(1024);
    hipLaunchKernelGGL(pq_fused, grid, block, 0, stream, X, C, out);
}